// Round 13
// baseline (305.804 us; speedup 1.0000x reference)
//
#include <hip/hip_runtime.h>

// PyFlowODE: Heun integration of dx/dt = (x - q(x,t))/t with Nadaraya-Watson
// Gaussian RBF retrieval. N=2048 queries (d=8), B=4096 bank, T=16 steps.
//
// Round-13 = round-11 with the ACC8 macro bug fixed (macro param `w`
// captured the `.w` member token -> lo.w0; now an inline function).
//  - LESSON r5 vs r10: VALU-busy time constant (~106 us) at 2 and 4 waves/SIMD
//    -> instruction-count bound, not latency. This round cuts ops/pair.
//  - ||z||^2 EXPANSION: logit = c0*||x||^2 - 2*alpha*c0*<x,x0> + c0*a^2*||x0||^2.
//    ||x0_b||^2 precomputed once in LDS (16 KB). Per (query,entry): 8-FMA dot
//    + 2-FMA logit + exp2 + 9 accum  (~21 ops vs 27 zz-form).
//  - 2 queries/wave over QUARTER bank (16 entries/lane): halves LDS visits.
//    r9's spill came from __launch_bounds__(1024,4)'s 64-VGPR clamp; here
//    __launch_bounds__(1024) leaves the natural 128 cap (~104 live VGPR).
//  - Max-domain online softmax; FIRST BATCH PEELED for exact M init; deferred
//    rescale (threshold 40 log2) with monotone M.
//  - t=1 eval: alpha=0 -> uniform weights -> q = mean(x0) exactly; deleted.

#define NQ     2048
#define NB     4096
#define TSTEPS 16
#define BLOCK  1024
#define NWAVE  16

#if defined(__has_builtin)
#if __has_builtin(__builtin_amdgcn_exp2f)
#define EXP2(x) __builtin_amdgcn_exp2f(x)
#endif
#endif
#ifndef EXP2
#define EXP2(x) exp2f(x)
#endif

__device__ __forceinline__ float dot8(const float (&x)[8], const float4& lo,
                                      const float4& hi) {
    float d = x[0] * lo.x;
    d = fmaf(x[1], lo.y, d);
    d = fmaf(x[2], lo.z, d);
    d = fmaf(x[3], lo.w, d);
    d = fmaf(x[4], hi.x, d);
    d = fmaf(x[5], hi.y, d);
    d = fmaf(x[6], hi.z, d);
    d = fmaf(x[7], hi.w, d);
    return d;
}

__device__ __forceinline__ void acc8(float (&q)[8], float wt,
                                     const float4& lo, const float4& hi) {
    q[0] = fmaf(wt, lo.x, q[0]);
    q[1] = fmaf(wt, lo.y, q[1]);
    q[2] = fmaf(wt, lo.z, q[2]);
    q[3] = fmaf(wt, lo.w, q[3]);
    q[4] = fmaf(wt, hi.x, q[4]);
    q[5] = fmaf(wt, hi.y, q[5]);
    q[6] = fmaf(wt, hi.z, q[6]);
    q[7] = fmaf(wt, hi.w, q[7]);
}

// Evaluate G(xe, t) for this wave's TWO queries. Wave covers bank quarter
// `quad`; 4 waves per query-pair merge via mrg (g0 = w & ~3).
__device__ __forceinline__ void eval_pair(
        const float4* __restrict__ lds_lo,
        const float4* __restrict__ lds_hi,
        const float*  __restrict__ lds_n0,
        float (*mrg)[2][10],
        const float (&xe)[2][8], float t, int lane, int quad, int w,
        float (&Gout)[2][8])
{
    const float c0 = -0.72134752044448170f / (t * t);   // -0.5*log2(e)/t^2
    const float al = 1.0f - t;
    const float A  = c0 * al * al;
    const float Bc = -2.0f * al * c0;

    float M[2], s[2], base[2], q[2][8];
    const int b0 = quad * 1024 + lane;   // 16 entries/lane, stride 64

    // ---- peel batch 0 (entries b0, b0+64): exact running-max init ----
    {
        const float4 lo0 = lds_lo[b0],      hi0 = lds_hi[b0];
        const float4 lo1 = lds_lo[b0 + 64], hi1 = lds_hi[b0 + 64];
        const float  n0a = lds_n0[b0],      n0b = lds_n0[b0 + 64];
#pragma unroll
        for (int qq = 0; qq < 2; ++qq) {
            float px = xe[qq][0] * xe[qq][0];
#pragma unroll
            for (int j = 1; j < 8; ++j) px = fmaf(xe[qq][j], xe[qq][j], px);
            float bb = c0 * px;
            const float d0 = dot8(xe[qq], lo0, hi0);
            const float d1 = dot8(xe[qq], lo1, hi1);
            const float l0 = fmaf(Bc, d0, fmaf(A, n0a, bb));
            const float l1 = fmaf(Bc, d1, fmaf(A, n0b, bb));
            const float m  = fmaxf(l0, l1);
            M[qq]    = m;
            base[qq] = bb - m;
            const float w0 = EXP2(l0 - m);
            const float w1 = EXP2(l1 - m);
            s[qq] = w0 + w1;
            q[qq][0] = w0 * lo0.x; q[qq][1] = w0 * lo0.y;
            q[qq][2] = w0 * lo0.z; q[qq][3] = w0 * lo0.w;
            q[qq][4] = w0 * hi0.x; q[qq][5] = w0 * hi0.y;
            q[qq][6] = w0 * hi0.z; q[qq][7] = w0 * hi0.w;
            acc8(q[qq], w1, lo1, hi1);
        }
    }

    // ---- batches 1..7 (2 entries each), deferred rescale ----
#pragma unroll
    for (int g = 1; g < 8; ++g) {
        const int b = b0 + g * 128;
        const float4 lo0 = lds_lo[b],      hi0 = lds_hi[b];
        const float4 lo1 = lds_lo[b + 64], hi1 = lds_hi[b + 64];
        const float  n0a = lds_n0[b],      n0b = lds_n0[b + 64];
        float l[2][2];
#pragma unroll
        for (int qq = 0; qq < 2; ++qq) {
            const float d0 = dot8(xe[qq], lo0, hi0);
            const float d1 = dot8(xe[qq], lo1, hi1);
            l[qq][0] = fmaf(Bc, d0, fmaf(A, n0a, base[qq]));
            l[qq][1] = fmaf(Bc, d1, fmaf(A, n0b, base[qq]));
        }
        const float bl = fmaxf(fmaxf(l[0][0], l[0][1]),
                               fmaxf(l[1][0], l[1][1]));
        if (__any(bl > 40.0f)) {           // rare, wave-uniform branch
#pragma unroll
            for (int qq = 0; qq < 2; ++qq) {
                const float blq = fmaxf(l[qq][0], l[qq][1]);
                const float D   = fmaxf(blq, 0.0f);
                const float c   = EXP2(-D);
                s[qq] *= c;
#pragma unroll
                for (int j = 0; j < 8; ++j) q[qq][j] *= c;
                base[qq] -= D;
                l[qq][0] -= D;
                l[qq][1] -= D;
                M[qq]    += D;
            }
        }
#pragma unroll
        for (int qq = 0; qq < 2; ++qq) {
            const float w0 = EXP2(l[qq][0]);   // may exceed 1 (bounded 2^40)
            const float w1 = EXP2(l[qq][1]);
            s[qq] += w0;
            acc8(q[qq], w0, lo0, hi0);
            s[qq] += w1;
            acc8(q[qq], w1, lo1, hi1);
        }
    }

    // ---- per-wave cross-lane reduce (max-domain butterfly) ----
#pragma unroll
    for (int qq = 0; qq < 2; ++qq) {
        float mw = M[qq];
#pragma unroll
        for (int off = 32; off >= 1; off >>= 1)
            mw = fmaxf(mw, __shfl_xor(mw, off));
        const float c = EXP2(M[qq] - mw);   // <= 1
        s[qq] *= c;
#pragma unroll
        for (int j = 0; j < 8; ++j) q[qq][j] *= c;
        M[qq] = mw;
#pragma unroll
        for (int off = 32; off >= 1; off >>= 1) {
            s[qq] += __shfl_xor(s[qq], off);
#pragma unroll
            for (int j = 0; j < 8; ++j) q[qq][j] += __shfl_xor(q[qq][j], off);
        }
    }

    // ---- cross-wave 4-way merge via LDS ----
    if (lane == 0) {
#pragma unroll
        for (int qq = 0; qq < 2; ++qq) {
            float* p = mrg[w][qq];
            p[0] = M[qq];
            p[1] = s[qq];
#pragma unroll
            for (int j = 0; j < 8; ++j) p[2 + j] = q[qq][j];
        }
    }
    __syncthreads();
    const int g0 = w & ~3;
    const float invT = 1.0f / t;
#pragma unroll
    for (int qq = 0; qq < 2; ++qq) {
        float mk[4], sk[4];
#pragma unroll
        for (int k = 0; k < 4; ++k) {
            mk[k] = mrg[g0 + k][qq][0];
            sk[k] = mrg[g0 + k][qq][1];
        }
        const float Mx = fmaxf(fmaxf(mk[0], mk[1]), fmaxf(mk[2], mk[3]));
        float ck[4];
        float S = 0.0f;
#pragma unroll
        for (int k = 0; k < 4; ++k) {
            ck[k] = EXP2(mk[k] - Mx);
            S = fmaf(ck[k], sk[k], S);
        }
        const float invS = 1.0f / S;
#pragma unroll
        for (int j = 0; j < 8; ++j) {
            float Q = 0.0f;
#pragma unroll
            for (int k = 0; k < 4; ++k)
                Q = fmaf(ck[k], mrg[g0 + k][qq][2 + j], Q);
            Gout[qq][j] = fmaf(-Q, invS, xe[qq][j]) * invT;
        }
    }
    __syncthreads();   // protect mrg before next eval's write
}

__global__ __launch_bounds__(BLOCK) void flow_ode_kernel(
        const float* __restrict__ x1,
        const float* __restrict__ x0,
        float* __restrict__ out)
{
    __shared__ float4 lds_lo[NB];          // x0[b][0:4]   64 KB
    __shared__ float4 lds_hi[NB];          // x0[b][4:8]   64 KB
    __shared__ float  lds_n0[NB];          // ||x0_b||^2   16 KB
    __shared__ float  mrg[NWAVE][2][10];   // merge buffer

    const int tid  = threadIdx.x;
    const int w    = tid >> 6;
    const int lane = tid & 63;

    // ---- stage x0 + n0 (144 KB) + partial column sums for mean ----
    float sm[8];
#pragma unroll
    for (int j = 0; j < 8; ++j) sm[j] = 0.0f;
#pragma unroll
    for (int i = 0; i < NB / BLOCK; ++i) {
        const int b = tid + i * BLOCK;
        const float4* p = reinterpret_cast<const float4*>(x0) + 2 * b;
        const float4 lo = p[0], hi = p[1];
        lds_lo[b] = lo;
        lds_hi[b] = hi;
        float n0 = lo.x * lo.x;
        n0 = fmaf(lo.y, lo.y, n0); n0 = fmaf(lo.z, lo.z, n0);
        n0 = fmaf(lo.w, lo.w, n0); n0 = fmaf(hi.x, hi.x, n0);
        n0 = fmaf(hi.y, hi.y, n0); n0 = fmaf(hi.z, hi.z, n0);
        n0 = fmaf(hi.w, hi.w, n0);
        lds_n0[b] = n0;
        sm[0] += lo.x; sm[1] += lo.y; sm[2] += lo.z; sm[3] += lo.w;
        sm[4] += hi.x; sm[5] += hi.y; sm[6] += hi.z; sm[7] += hi.w;
    }
#pragma unroll
    for (int off = 32; off >= 1; off >>= 1)
#pragma unroll
        for (int j = 0; j < 8; ++j) sm[j] += __shfl_xor(sm[j], off);
    if (lane == 0) {
#pragma unroll
        for (int j = 0; j < 8; ++j) mrg[w][0][j] = sm[j];
    }
    __syncthreads();
    float mean[8];
#pragma unroll
    for (int j = 0; j < 8; ++j) {
        float acc = 0.0f;
#pragma unroll
        for (int wv = 0; wv < NWAVE; ++wv) acc += mrg[wv][0][j];
        mean[j] = acc * (1.0f / (float)NB);
    }
    __syncthreads();

    // ---- wave -> query-pair assignment: 4 waves per pair, quarter banks ----
    const int quad  = w & 3;
    const int pair  = w >> 2;
    const int qbase = blockIdx.x * 8 + pair * 2;

    float xt[2][8], G1[2][8];
#pragma unroll
    for (int qq = 0; qq < 2; ++qq) {
        const float4* p = reinterpret_cast<const float4*>(x1) + 2 * (qbase + qq);
        const float4 a = p[0], b4 = p[1];
        xt[qq][0] = a.x;  xt[qq][1] = a.y;  xt[qq][2] = a.z;  xt[qq][3] = a.w;
        xt[qq][4] = b4.x; xt[qq][5] = b4.y; xt[qq][6] = b4.z; xt[qq][7] = b4.w;
    }
    // G1 at t=1: alpha=0 -> uniform weights -> q = mean(x0) exactly
#pragma unroll
    for (int qq = 0; qq < 2; ++qq)
#pragma unroll
        for (int j = 0; j < 8; ++j) G1[qq][j] = xt[qq][j] - mean[j];

    const float hstep = 0.0625f;   // 1/16
    for (int i = 1; i < TSTEPS; ++i) {
        const float t = 1.0f - hstep * (float)i;   // exact in f32
        float xe[2][8], G2[2][8];
#pragma unroll
        for (int qq = 0; qq < 2; ++qq)
#pragma unroll
            for (int j = 0; j < 8; ++j)
                xe[qq][j] = fmaf(-hstep, G1[qq][j], xt[qq][j]);   // Euler predictor
        eval_pair(lds_lo, lds_hi, lds_n0, mrg, xe, t, lane, quad, w, G2);
#pragma unroll
        for (int qq = 0; qq < 2; ++qq)
#pragma unroll
            for (int j = 0; j < 8; ++j) {
                xt[qq][j] = fmaf(-0.03125f, G1[qq][j] + G2[qq][j], xt[qq][j]);
                G1[qq][j] = G2[qq][j];
            }
    }

    if (quad == 0 && lane == 0) {
#pragma unroll
        for (int qq = 0; qq < 2; ++qq) {
            float4 a, b4;
            a.x  = xt[qq][0]; a.y  = xt[qq][1]; a.z  = xt[qq][2]; a.w  = xt[qq][3];
            b4.x = xt[qq][4]; b4.y = xt[qq][5]; b4.z = xt[qq][6]; b4.w = xt[qq][7];
            float4* o = reinterpret_cast<float4*>(out + (qbase + qq) * 8);
            o[0] = a;
            o[1] = b4;
        }
    }
}

extern "C" void kernel_launch(void* const* d_in, const int* in_sizes, int n_in,
                              void* d_out, int out_size, void* d_ws, size_t ws_size,
                              hipStream_t stream) {
    const float* x1 = (const float*)d_in[0];   // (2048, 8)
    const float* x0 = (const float*)d_in[1];   // (4096, 8)
    float* out = (float*)d_out;                // (2048, 8)

    flow_ode_kernel<<<NQ / 8, BLOCK, 0, stream>>>(x1, x0, out);
}

// Round 14
// 175.640 us; speedup vs baseline: 1.7411x; 1.7411x over previous
//
#include <hip/hip_runtime.h>

// PyFlowODE: Heun integration of dx/dt = (x - q(x,t))/t with Nadaraya-Watson
// Gaussian RBF retrieval. N=2048 queries (d=8), B=4096 bank, T=16 steps.
//
// Round-14 structure:
//  - TOOLCHAIN LESSON (r9 + r13): 1024-thread blocks clamp VGPR to 64 when
//    pressure > 64 -> massive scratch spill (FETCH 200+ MB). 512-thread
//    blocks allow natural allocation (r5: 88 VGPR, no spill). So: 512 thr.
//  - OCCUPANCY LESSON (r10): 2 -> 4 waves/SIMD moved dur only 150 -> 143;
//    VALU-busy ~106 us constant -> instruction-count bound. Only lever:
//    fewer VALU instructions.
//  - ||z||^2 EXPANSION (validated on HW in r13, absmax 4.9e-4):
//    logit = c0||x||^2 + Bc<x,x0> + A||x0||^2, n0=||x0||^2 staged in LDS.
//  - float2 (pkmul/pkfma) forms for dot + q-accumulate: invites
//    v_pk_fma_f32 (VOP3P packed f32). Fallback = scalar (r13 op count).
//  - Geometry: 8 waves/block; 2 queries/wave over HALF bank (32 entr/lane,
//    16 batches x 2 entries); 2-way pair merge via LDS (r5-proven,
//    bit-identical across the pair).
//  - Max-domain online softmax; batch-0 peel for exact M init; deferred
//    rescale (threshold 40 log2-units).
//  - t=1 eval: alpha=0 -> uniform weights -> q = mean(x0) exactly; deleted.

#define NQ     2048
#define NB     4096
#define TSTEPS 16
#define BLOCK  512
#define NWAVE  8

#if defined(__has_builtin)
#if __has_builtin(__builtin_amdgcn_exp2f)
#define EXP2(x) __builtin_amdgcn_exp2f(x)
#endif
#endif
#ifndef EXP2
#define EXP2(x) exp2f(x)
#endif

__device__ __forceinline__ float2 pkmul(float2 a, float2 b) {
    return make_float2(a.x * b.x, a.y * b.y);
}
__device__ __forceinline__ float2 pkfma(float2 a, float2 b, float2 c) {
    return make_float2(fmaf(a.x, b.x, c.x), fmaf(a.y, b.y, c.y));
}

// Evaluate G(xe, t) for this wave's TWO queries. Wave covers bank half `h`;
// partials merged with partner wave (w^1) via mrg.
__device__ __forceinline__ void eval_pair(
        const float4* __restrict__ lds_lo,
        const float4* __restrict__ lds_hi,
        const float*  __restrict__ lds_n0,
        float (*mrg)[2][10],
        const float (&xe)[2][8], float t, int lane, int h, int w,
        float (&Gout)[2][8])
{
    const float c0 = -0.72134752044448170f / (t * t);   // -0.5*log2(e)/t^2
    const float al = 1.0f - t;
    const float A  = c0 * al * al;
    const float Bc = -2.0f * al * c0;

    // float2 views of the two queries
    float2 xq2[2][4];
#pragma unroll
    for (int qq = 0; qq < 2; ++qq)
#pragma unroll
        for (int k = 0; k < 4; ++k)
            xq2[qq][k] = make_float2(xe[qq][2 * k], xe[qq][2 * k + 1]);

    float M[2], s[2], base[2];
    float2 q2[2][4];
    const int b0 = h * 2048 + lane;     // half bank: 32 entries/lane

    // ---- peel batch 0 (entries b0, b0+64): exact running-max init ----
    {
        const float4 LO0 = lds_lo[b0],      HI0 = lds_hi[b0];
        const float4 LO1 = lds_lo[b0 + 64], HI1 = lds_hi[b0 + 64];
        const float  n0a = lds_n0[b0],      n0b = lds_n0[b0 + 64];
        const float2 e0[4] = {make_float2(LO0.x, LO0.y), make_float2(LO0.z, LO0.w),
                              make_float2(HI0.x, HI0.y), make_float2(HI0.z, HI0.w)};
        const float2 e1[4] = {make_float2(LO1.x, LO1.y), make_float2(LO1.z, LO1.w),
                              make_float2(HI1.x, HI1.y), make_float2(HI1.z, HI1.w)};
#pragma unroll
        for (int qq = 0; qq < 2; ++qq) {
            float2 p2 = pkmul(xq2[qq][0], xq2[qq][0]);
            p2 = pkfma(xq2[qq][1], xq2[qq][1], p2);
            p2 = pkfma(xq2[qq][2], xq2[qq][2], p2);
            p2 = pkfma(xq2[qq][3], xq2[qq][3], p2);
            const float bb = c0 * (p2.x + p2.y);

            float2 d2 = pkmul(xq2[qq][0], e0[0]);
            d2 = pkfma(xq2[qq][1], e0[1], d2);
            d2 = pkfma(xq2[qq][2], e0[2], d2);
            d2 = pkfma(xq2[qq][3], e0[3], d2);
            const float l0 = fmaf(Bc, d2.x + d2.y, fmaf(A, n0a, bb));

            d2 = pkmul(xq2[qq][0], e1[0]);
            d2 = pkfma(xq2[qq][1], e1[1], d2);
            d2 = pkfma(xq2[qq][2], e1[2], d2);
            d2 = pkfma(xq2[qq][3], e1[3], d2);
            const float l1 = fmaf(Bc, d2.x + d2.y, fmaf(A, n0b, bb));

            const float m = fmaxf(l0, l1);
            M[qq]    = m;
            base[qq] = bb - m;
            const float w0 = EXP2(l0 - m);
            const float w1 = EXP2(l1 - m);
            s[qq] = w0 + w1;
            const float2 w02 = make_float2(w0, w0);
            const float2 w12 = make_float2(w1, w1);
#pragma unroll
            for (int k = 0; k < 4; ++k)
                q2[qq][k] = pkfma(w12, e1[k], pkmul(w02, e0[k]));
        }
    }

    // ---- batches 1..15 (2 entries each), deferred rescale ----
#pragma unroll 4
    for (int g = 1; g < 16; ++g) {
        const int b = b0 + g * 128;
        const float4 LO0 = lds_lo[b],      HI0 = lds_hi[b];
        const float4 LO1 = lds_lo[b + 64], HI1 = lds_hi[b + 64];
        const float  n0a = lds_n0[b],      n0b = lds_n0[b + 64];
        const float2 e0[4] = {make_float2(LO0.x, LO0.y), make_float2(LO0.z, LO0.w),
                              make_float2(HI0.x, HI0.y), make_float2(HI0.z, HI0.w)};
        const float2 e1[4] = {make_float2(LO1.x, LO1.y), make_float2(LO1.z, LO1.w),
                              make_float2(HI1.x, HI1.y), make_float2(HI1.z, HI1.w)};
        float l[2][2];
#pragma unroll
        for (int qq = 0; qq < 2; ++qq) {
            float2 d2 = pkmul(xq2[qq][0], e0[0]);
            d2 = pkfma(xq2[qq][1], e0[1], d2);
            d2 = pkfma(xq2[qq][2], e0[2], d2);
            d2 = pkfma(xq2[qq][3], e0[3], d2);
            l[qq][0] = fmaf(Bc, d2.x + d2.y, fmaf(A, n0a, base[qq]));

            d2 = pkmul(xq2[qq][0], e1[0]);
            d2 = pkfma(xq2[qq][1], e1[1], d2);
            d2 = pkfma(xq2[qq][2], e1[2], d2);
            d2 = pkfma(xq2[qq][3], e1[3], d2);
            l[qq][1] = fmaf(Bc, d2.x + d2.y, fmaf(A, n0b, base[qq]));
        }
        const float bl = fmaxf(fmaxf(l[0][0], l[0][1]),
                               fmaxf(l[1][0], l[1][1]));
        if (__any(bl > 40.0f)) {           // rare, wave-uniform branch
#pragma unroll
            for (int qq = 0; qq < 2; ++qq) {
                const float blq = fmaxf(l[qq][0], l[qq][1]);
                const float D   = fmaxf(blq, 0.0f);
                const float c   = EXP2(-D);
                const float2 c2 = make_float2(c, c);
                s[qq] *= c;
#pragma unroll
                for (int k = 0; k < 4; ++k) q2[qq][k] = pkmul(c2, q2[qq][k]);
                base[qq] -= D;
                l[qq][0] -= D;
                l[qq][1] -= D;
                M[qq]    += D;
            }
        }
#pragma unroll
        for (int qq = 0; qq < 2; ++qq) {
            const float w0 = EXP2(l[qq][0]);   // may exceed 1 (bounded 2^40)
            const float w1 = EXP2(l[qq][1]);
            s[qq] += w0 + w1;
            const float2 w02 = make_float2(w0, w0);
            const float2 w12 = make_float2(w1, w1);
#pragma unroll
            for (int k = 0; k < 4; ++k) {
                q2[qq][k] = pkfma(w02, e0[k], q2[qq][k]);
                q2[qq][k] = pkfma(w12, e1[k], q2[qq][k]);
            }
        }
    }

    // ---- per-wave cross-lane reduce (max-domain butterfly) ----
#pragma unroll
    for (int qq = 0; qq < 2; ++qq) {
        float mw = M[qq];
#pragma unroll
        for (int off = 32; off >= 1; off >>= 1)
            mw = fmaxf(mw, __shfl_xor(mw, off));
        const float c = EXP2(M[qq] - mw);   // <= 1
        const float2 c2 = make_float2(c, c);
        s[qq] *= c;
#pragma unroll
        for (int k = 0; k < 4; ++k) q2[qq][k] = pkmul(c2, q2[qq][k]);
        M[qq] = mw;
#pragma unroll
        for (int off = 32; off >= 1; off >>= 1) {
            s[qq] += __shfl_xor(s[qq], off);
#pragma unroll
            for (int k = 0; k < 4; ++k) {
                q2[qq][k].x += __shfl_xor(q2[qq][k].x, off);
                q2[qq][k].y += __shfl_xor(q2[qq][k].y, off);
            }
        }
    }

    // ---- cross-wave (pair) merge via LDS ----
    if (lane == 0) {
#pragma unroll
        for (int qq = 0; qq < 2; ++qq) {
            float* p = mrg[w][qq];
            p[0] = M[qq];
            p[1] = s[qq];
#pragma unroll
            for (int k = 0; k < 4; ++k) {
                p[2 + 2 * k]     = q2[qq][k].x;
                p[2 + 2 * k + 1] = q2[qq][k].y;
            }
        }
    }
    __syncthreads();
    const float invT = 1.0f / t;
#pragma unroll
    for (int qq = 0; qq < 2; ++qq) {
        const float* p = mrg[w ^ 1][qq];
        const float Mb = p[0], sb = p[1];
        const float Mx = fmaxf(M[qq], Mb);
        const float ca = EXP2(M[qq] - Mx);
        const float cb = EXP2(Mb    - Mx);
        const float S  = ca * s[qq] + cb * sb;   // commutative add: bit-identical
        const float invS = 1.0f / S;
#pragma unroll
        for (int k = 0; k < 4; ++k) {
            const float Qx = ca * q2[qq][k].x + cb * p[2 + 2 * k];
            const float Qy = ca * q2[qq][k].y + cb * p[2 + 2 * k + 1];
            Gout[qq][2 * k]     = fmaf(-Qx, invS, xe[qq][2 * k]) * invT;
            Gout[qq][2 * k + 1] = fmaf(-Qy, invS, xe[qq][2 * k + 1]) * invT;
        }
    }
    __syncthreads();   // protect mrg before next eval's write
}

__global__ __launch_bounds__(BLOCK) void flow_ode_kernel(
        const float* __restrict__ x1,
        const float* __restrict__ x0,
        float* __restrict__ out)
{
    __shared__ float4 lds_lo[NB];          // x0[b][0:4]   64 KB
    __shared__ float4 lds_hi[NB];          // x0[b][4:8]   64 KB
    __shared__ float  lds_n0[NB];          // ||x0_b||^2   16 KB
    __shared__ float  mrg[NWAVE][2][10];   // merge buffer

    const int tid  = threadIdx.x;
    const int w    = tid >> 6;
    const int lane = tid & 63;

    // ---- stage x0 + n0 (144 KB) + partial column sums for mean ----
    float sm[8];
#pragma unroll
    for (int j = 0; j < 8; ++j) sm[j] = 0.0f;
#pragma unroll
    for (int i = 0; i < NB / BLOCK; ++i) {
        const int b = tid + i * BLOCK;
        const float4* p = reinterpret_cast<const float4*>(x0) + 2 * b;
        const float4 lo = p[0], hi = p[1];
        lds_lo[b] = lo;
        lds_hi[b] = hi;
        float n0 = lo.x * lo.x;
        n0 = fmaf(lo.y, lo.y, n0); n0 = fmaf(lo.z, lo.z, n0);
        n0 = fmaf(lo.w, lo.w, n0); n0 = fmaf(hi.x, hi.x, n0);
        n0 = fmaf(hi.y, hi.y, n0); n0 = fmaf(hi.z, hi.z, n0);
        n0 = fmaf(hi.w, hi.w, n0);
        lds_n0[b] = n0;
        sm[0] += lo.x; sm[1] += lo.y; sm[2] += lo.z; sm[3] += lo.w;
        sm[4] += hi.x; sm[5] += hi.y; sm[6] += hi.z; sm[7] += hi.w;
    }
#pragma unroll
    for (int off = 32; off >= 1; off >>= 1)
#pragma unroll
        for (int j = 0; j < 8; ++j) sm[j] += __shfl_xor(sm[j], off);
    if (lane == 0) {
#pragma unroll
        for (int j = 0; j < 8; ++j) mrg[w][0][j] = sm[j];
    }
    __syncthreads();
    float mean[8];
#pragma unroll
    for (int j = 0; j < 8; ++j) {
        float acc = 0.0f;
#pragma unroll
        for (int wv = 0; wv < NWAVE; ++wv) acc += mrg[wv][0][j];
        mean[j] = acc * (1.0f / (float)NB);
    }
    __syncthreads();

    // ---- wave -> query assignment: 2 waves per query-pair, half banks ----
    const int h     = w & 1;
    const int pair  = w >> 1;
    const int qbase = blockIdx.x * 8 + pair * 2;

    float xt[2][8], G1[2][8];
#pragma unroll
    for (int qq = 0; qq < 2; ++qq) {
        const float4* p = reinterpret_cast<const float4*>(x1) + 2 * (qbase + qq);
        const float4 a = p[0], b4 = p[1];
        xt[qq][0] = a.x;  xt[qq][1] = a.y;  xt[qq][2] = a.z;  xt[qq][3] = a.w;
        xt[qq][4] = b4.x; xt[qq][5] = b4.y; xt[qq][6] = b4.z; xt[qq][7] = b4.w;
    }
    // G1 at t=1: alpha=0 -> uniform weights -> q = mean(x0) exactly
#pragma unroll
    for (int qq = 0; qq < 2; ++qq)
#pragma unroll
        for (int j = 0; j < 8; ++j) G1[qq][j] = xt[qq][j] - mean[j];

    const float hstep = 0.0625f;   // 1/16
    for (int i = 1; i < TSTEPS; ++i) {
        const float t = 1.0f - hstep * (float)i;   // exact in f32
        float xe[2][8], G2[2][8];
#pragma unroll
        for (int qq = 0; qq < 2; ++qq)
#pragma unroll
            for (int j = 0; j < 8; ++j)
                xe[qq][j] = fmaf(-hstep, G1[qq][j], xt[qq][j]);   // Euler predictor
        eval_pair(lds_lo, lds_hi, lds_n0, mrg, xe, t, lane, h, w, G2);
#pragma unroll
        for (int qq = 0; qq < 2; ++qq)
#pragma unroll
            for (int j = 0; j < 8; ++j) {
                xt[qq][j] = fmaf(-0.03125f, G1[qq][j] + G2[qq][j], xt[qq][j]);
                G1[qq][j] = G2[qq][j];
            }
    }

    if (h == 0 && lane == 0) {
#pragma unroll
        for (int qq = 0; qq < 2; ++qq) {
            float4 a, b4;
            a.x  = xt[qq][0]; a.y  = xt[qq][1]; a.z  = xt[qq][2]; a.w  = xt[qq][3];
            b4.x = xt[qq][4]; b4.y = xt[qq][5]; b4.z = xt[qq][6]; b4.w = xt[qq][7];
            float4* o = reinterpret_cast<float4*>(out + (qbase + qq) * 8);
            o[0] = a;
            o[1] = b4;
        }
    }
}

extern "C" void kernel_launch(void* const* d_in, const int* in_sizes, int n_in,
                              void* d_out, int out_size, void* d_ws, size_t ws_size,
                              hipStream_t stream) {
    const float* x1 = (const float*)d_in[0];   // (2048, 8)
    const float* x0 = (const float*)d_in[1];   // (4096, 8)
    float* out = (float*)d_out;                // (2048, 8)

    flow_ode_kernel<<<NQ / 8, BLOCK, 0, stream>>>(x1, x0, out);
}